// Round 1
// baseline (133.582 us; speedup 1.0000x reference)
//
#include <hip/hip_runtime.h>
#include <math.h>

// Hit-miss transform: out[i][j] = min_{di,dj}(x[i+di][j+dj] - Khit[di][dj])
//                               - max_{di,dj}(x[i+di][j+dj] - Kmiss[di][dj])
// H=W=4096 fp32 input, 5x5 kernels, output 4092x4092 fp32.

constexpr int KS = 5;
constexpr int HH = 4096;
constexpr int WW = 4096;
constexpr int HO = HH - (KS - 1);   // 4092
constexpr int WO = WW - (KS - 1);   // 4092

__global__ __launch_bounds__(256) void hitmiss_kernel(
    const float* __restrict__ x,
    const float* __restrict__ kh,
    const float* __restrict__ km,
    float* __restrict__ out)
{
    const int g   = blockIdx.x * blockDim.x + threadIdx.x;  // column group (4 outputs)
    const int row = blockIdx.y;                             // output row
    const int j0  = g * 4;
    if (j0 >= WO) return;

    // Kernel weights: uniform addresses -> scalar loads into SGPRs.
    float khr[KS * KS], kmr[KS * KS];
#pragma unroll
    for (int i = 0; i < KS * KS; ++i) {
        khr[i] = kh[i];
        kmr[i] = km[i];
    }

    float mn[4], mx[4];
#pragma unroll
    for (int p = 0; p < 4; ++p) {
        mn[p] = INFINITY;
        mx[p] = -INFINITY;
    }

#pragma unroll
    for (int di = 0; di < KS; ++di) {
        const float* rp = x + (size_t)(row + di) * WW + j0;
        // 8 contiguous input floats cover the 5-wide window for 4 outputs.
        float4 a = *reinterpret_cast<const float4*>(rp);
        float4 b = *reinterpret_cast<const float4*>(rp + 4);
        float v[8] = {a.x, a.y, a.z, a.w, b.x, b.y, b.z, b.w};
#pragma unroll
        for (int dj = 0; dj < KS; ++dj) {
            const float h = khr[di * KS + dj];
            const float m = kmr[di * KS + dj];
#pragma unroll
            for (int p = 0; p < 4; ++p) {
                mn[p] = fminf(mn[p], v[dj + p] - h);
                mx[p] = fmaxf(mx[p], v[dj + p] - m);
            }
        }
    }

    float4 o;
    o.x = mn[0] - mx[0];
    o.y = mn[1] - mx[1];
    o.z = mn[2] - mx[2];
    o.w = mn[3] - mx[3];
    *reinterpret_cast<float4*>(out + (size_t)row * WO + j0) = o;
}

extern "C" void kernel_launch(void* const* d_in, const int* in_sizes, int n_in,
                              void* d_out, int out_size, void* d_ws, size_t ws_size,
                              hipStream_t stream) {
    const float* x  = (const float*)d_in[0];
    const float* kh = (const float*)d_in[1];
    const float* km = (const float*)d_in[2];
    float* out = (float*)d_out;

    dim3 block(256, 1, 1);
    dim3 grid((WO / 4 + 255) / 256, HO, 1);  // 4 x 4092 blocks
    hipLaunchKernelGGL(hitmiss_kernel, grid, block, 0, stream, x, kh, km, out);
}

// Round 2
// 124.826 us; speedup vs baseline: 1.0701x; 1.0701x over previous
//
#include <hip/hip_runtime.h>
#include <math.h>

// Hit-miss transform: out[i][j] = min_{di,dj}(x[i+di][j+dj] - Khit[di][dj])
//                               - max_{di,dj}(x[i+di][j+dj] - Kmiss[di][dj])
// H=W=4096 fp32 input, 5x5 kernels, output 4092x4092 fp32.
//
// R2: 4x4 output tile per thread (1.0 float4-load per output vs 2.5 in R1),
// rolling 5-row register window with one-row-ahead prefetch, min/max chains
// shaped for v_min3/v_max3 fusion.

constexpr int KS = 5;
constexpr int HH = 4096;
constexpr int WW = 4096;
constexpr int HO = HH - (KS - 1);   // 4092
constexpr int WO = WW - (KS - 1);   // 4092
constexpr int CG = WO / 4;          // 1023 column groups

__global__ __launch_bounds__(256) void hitmiss_kernel(
    const float* __restrict__ x,
    const float* __restrict__ kh,
    const float* __restrict__ km,
    float* __restrict__ out)
{
    const int cg = blockIdx.x * blockDim.x + threadIdx.x;  // column group
    if (cg >= CG) return;
    const int j0 = cg * 4;
    const int r0 = blockIdx.y * 4;                          // first output row of tile

    // Kernel weights: uniform addresses -> scalar loads into SGPRs.
    float wh[KS * KS], wm[KS * KS];
#pragma unroll
    for (int i = 0; i < KS * KS; ++i) {
        wh[i] = kh[i];
        wm[i] = km[i];
    }

    // Rolling register window of input rows (8 rows touched per 4-row tile).
    float v[8][8];

#pragma unroll
    for (int r = 0; r < 5; ++r) {
        const float* rp = x + (size_t)(r0 + r) * WW + j0;
        float4 a = *reinterpret_cast<const float4*>(rp);
        float4 b = *reinterpret_cast<const float4*>(rp + 4);
        v[r][0] = a.x; v[r][1] = a.y; v[r][2] = a.z; v[r][3] = a.w;
        v[r][4] = b.x; v[r][5] = b.y; v[r][6] = b.z; v[r][7] = b.w;
    }

#pragma unroll
    for (int orow = 0; orow < 4; ++orow) {
        // Prefetch the row needed by the NEXT orow iteration: a full output
        // row of compute (~300 instrs) hides the load latency.
        if (orow < 3) {
            const int r = orow + 5;
            const float* rp = x + (size_t)(r0 + r) * WW + j0;
            float4 a = *reinterpret_cast<const float4*>(rp);
            float4 b = *reinterpret_cast<const float4*>(rp + 4);
            v[r][0] = a.x; v[r][1] = a.y; v[r][2] = a.z; v[r][3] = a.w;
            v[r][4] = b.x; v[r][5] = b.y; v[r][6] = b.z; v[r][7] = b.w;
        }

        float mn[4], mx[4];
#pragma unroll
        for (int p = 0; p < 4; ++p) {
            mn[p] = INFINITY;
            mx[p] = -INFINITY;
        }

#pragma unroll
        for (int di = 0; di < KS; ++di) {
            const float* row = v[orow + di];
#pragma unroll
            for (int dj = 0; dj < KS; ++dj) {
                const float h = wh[di * KS + dj];
                const float m = wm[di * KS + dj];
#pragma unroll
                for (int p = 0; p < 4; ++p) {
                    // acc = min(min(acc, a), b) folds to v_min3_f32 on gfx9xx
                    mn[p] = fminf(mn[p], row[dj + p] - h);
                    mx[p] = fmaxf(mx[p], row[dj + p] - m);
                }
            }
        }

        float4 o;
        o.x = mn[0] - mx[0];
        o.y = mn[1] - mx[1];
        o.z = mn[2] - mx[2];
        o.w = mn[3] - mx[3];
        *reinterpret_cast<float4*>(out + (size_t)(r0 + orow) * WO + j0) = o;
    }
}

extern "C" void kernel_launch(void* const* d_in, const int* in_sizes, int n_in,
                              void* d_out, int out_size, void* d_ws, size_t ws_size,
                              hipStream_t stream) {
    const float* x  = (const float*)d_in[0];
    const float* kh = (const float*)d_in[1];
    const float* km = (const float*)d_in[2];
    float* out = (float*)d_out;

    dim3 block(256, 1, 1);
    dim3 grid((CG + 255) / 256, HO / 4, 1);  // 4 x 1023 blocks
    hipLaunchKernelGGL(hitmiss_kernel, grid, block, 0, stream, x, kh, km, out);
}

// Round 3
// 124.820 us; speedup vs baseline: 1.0702x; 1.0000x over previous
//
#include <hip/hip_runtime.h>
#include <math.h>

// Hit-miss transform: out[i][j] = min_{di,dj}(x[i+di][j+dj] - Khit[di][dj])
//                               - max_{di,dj}(x[i+di][j+dj] - Kmiss[di][dj])
// H=W=4096 fp32 input, 5x5 kernels, output 4092x4092 fp32.
//
// R3: VALU-issue-bound fix. (1) inline-asm v_min3/v_max3 — compiler won't
// fold fminf chains without nnan, costing ~24 extra ops/pixel. (2) streaming
// 4-col x 6-row strip per thread with 6-deep cyclic register row window,
// fully unrolled (static indices, no window shuffles), prefetch one row ahead.

constexpr int KS  = 5;
constexpr int WW  = 4096;
constexpr int HO  = 4092;
constexpr int WO  = 4092;
constexpr int CG  = WO / 4;   // 1023 column groups
constexpr int RPT = 6;        // output rows per thread (4092 = 6*682)

__device__ __forceinline__ float min3f(float a, float b, float c) {
    float d;
    asm("v_min3_f32 %0, %1, %2, %3" : "=v"(d) : "v"(a), "v"(b), "v"(c));
    return d;
}
__device__ __forceinline__ float max3f(float a, float b, float c) {
    float d;
    asm("v_max3_f32 %0, %1, %2, %3" : "=v"(d) : "v"(a), "v"(b), "v"(c));
    return d;
}

__global__ __launch_bounds__(256) void hitmiss_kernel(
    const float* __restrict__ x,
    const float* __restrict__ kh,
    const float* __restrict__ km,
    float* __restrict__ out)
{
    const int cg = blockIdx.x * blockDim.x + threadIdx.x;  // column group
    if (cg >= CG) return;
    const int j0 = cg * 4;
    const int r0 = blockIdx.y * RPT;

    // Kernel weights: uniform addresses -> scalar loads into SGPRs.
    float wh[KS * KS], wm[KS * KS];
#pragma unroll
    for (int i = 0; i < KS * KS; ++i) {
        wh[i] = kh[i];
        wm[i] = km[i];
    }

    const float* base = x + (size_t)r0 * WW + j0;

    // 6-deep cyclic window of input rows; buf[i % 6] holds input row i.
    float buf[6][8];

#pragma unroll
    for (int r = 0; r < 5; ++r) {
        float4 a = *reinterpret_cast<const float4*>(base + (size_t)r * WW);
        float4 b = *reinterpret_cast<const float4*>(base + (size_t)r * WW + 4);
        buf[r][0] = a.x; buf[r][1] = a.y; buf[r][2] = a.z; buf[r][3] = a.w;
        buf[r][4] = b.x; buf[r][5] = b.y; buf[r][6] = b.z; buf[r][7] = b.w;
    }

#pragma unroll
    for (int r = 0; r < RPT; ++r) {
        // Prefetch input row r+5 into the slot holding (dead) row r-1.
        // Issued a full output row of compute before first use.
        if (r < RPT - 1) {
            const int slot = (r + 5) % 6;
            float4 a = *reinterpret_cast<const float4*>(base + (size_t)(r + 5) * WW);
            float4 b = *reinterpret_cast<const float4*>(base + (size_t)(r + 5) * WW + 4);
            buf[slot][0] = a.x; buf[slot][1] = a.y; buf[slot][2] = a.z; buf[slot][3] = a.w;
            buf[slot][4] = b.x; buf[slot][5] = b.y; buf[slot][6] = b.z; buf[slot][7] = b.w;
        }

        float mnA[4], mnP[4], mxA[4], mxP[4];

#pragma unroll
        for (int di = 0; di < KS; ++di) {
            const int br = (r + di) % 6;   // static after unroll
#pragma unroll
            for (int dj = 0; dj < KS; ++dj) {
                const int k = di * KS + dj;
                const float h = wh[k];
                const float m = wm[k];
#pragma unroll
                for (int p = 0; p < 4; ++p) {
                    const float v  = buf[br][dj + p];
                    const float th = v - h;
                    const float tm = v - m;
                    if (k == 0) {
                        mnA[p] = th; mxA[p] = tm;
                    } else if (k & 1) {
                        mnP[p] = th; mxP[p] = tm;
                    } else {
                        // folds terms (k-1, k): 12 min3 + 12 max3 per pixel
                        mnA[p] = min3f(mnA[p], mnP[p], th);
                        mxA[p] = max3f(mxA[p], mxP[p], tm);
                    }
                }
            }
        }

        float4 o;
        o.x = mnA[0] - mxA[0];
        o.y = mnA[1] - mxA[1];
        o.z = mnA[2] - mxA[2];
        o.w = mnA[3] - mxA[3];
        *reinterpret_cast<float4*>(out + (size_t)(r0 + r) * WO + j0) = o;
    }
}

extern "C" void kernel_launch(void* const* d_in, const int* in_sizes, int n_in,
                              void* d_out, int out_size, void* d_ws, size_t ws_size,
                              hipStream_t stream) {
    const float* x  = (const float*)d_in[0];
    const float* kh = (const float*)d_in[1];
    const float* km = (const float*)d_in[2];
    float* out = (float*)d_out;

    dim3 block(256, 1, 1);
    dim3 grid((CG + 255) / 256, HO / RPT, 1);  // 4 x 682 blocks
    hipLaunchKernelGGL(hitmiss_kernel, grid, block, 0, stream, x, kh, km, out);
}